// Round 17
// baseline (396.732 us; speedup 1.0000x reference)
//
#include <hip/hip_runtime.h>
#include <hip/hip_bf16.h>
#include <math.h>

#define N_NODES 50000
#define E_EDGES 262144
#define D_FEAT  128
#define H_HID   256
#define NEXP    4

typedef __attribute__((ext_vector_type(8))) short  short8;
typedef __attribute__((ext_vector_type(4))) float  floatx4;

// ws layout:
//   [0..15]                      float probsum[4]
//   [16..31]                     unsigned count[4]
//   [32 .. 32+16*E)              int lists[4][E]
//   [+4*E)                       float pval[E]
//   [+512K)                      ushort w1b[262144]  (bf16, B-fragment-linear)
//   [+8K)                        double gwd[128*8]   (g2|g3 rows as f64)
//   [+3.2M)                      double nodeTab[N][8] (z.g0 | z.g1 in f64)
#define W1B_OFF0 0
#define W1B_OFF1 65536      // 256*256
#define W1B_OFF2 98304      // +128*256
#define W1B_OFF3 131072     // +128*256

__device__ __forceinline__ unsigned short f2bf(float f) {
    __hip_bfloat16 h = __float2bfloat16(f);       // RNE
    return *reinterpret_cast<unsigned short*>(&h);
}

// ---------------------------------------------------------------------------
// Phase 0 (merged): blocks 0..1023 convert W1 -> bf16 B-fragment layout;
// blocks 1024..1219 compute per-node linear gate contributions (f64) + gwd.
// ---------------------------------------------------------------------------
__global__ __launch_bounds__(256) void prep_kernel(
    const float* __restrict__ cw1, const float* __restrict__ dw1,
    const float* __restrict__ mw1, const float* __restrict__ aw1,
    unsigned short* __restrict__ w1b,
    const float* __restrict__ z, const float* __restrict__ gw,
    double* __restrict__ nodeTab, double* __restrict__ gwd)
{
    int bx  = blockIdx.x;
    int tid = threadIdx.x;

    if (bx < 1024) {
        // ---- conv: w1b[off + ((k>>3)*256 + n)*8 + (k&7)] = bf16(w1[k*256+n])
        int r = bx, n = tid;
        const float* src; int k, off;
        if (r < 256)      { src = cw1; k = r;       off = W1B_OFF0; }
        else if (r < 384) { src = dw1; k = r - 256; off = W1B_OFF1; }
        else if (r < 512) { src = mw1; k = r - 384; off = W1B_OFF2; }
        else              { src = aw1; k = r - 512; off = W1B_OFF3; }
        w1b[off + (((k >> 3) * 256 + n) << 3) + (k & 7)] = f2bf(src[k * 256 + n]);
        return;
    }

    int n = (bx - 1024) * 256 + tid;
    if (n < 128) {
        #pragma unroll
        for (int k = 0; k < 4; ++k) {
            gwd[n * 8 + k]     = (double)gw[4 * (256 + n) + k];
            gwd[n * 8 + 4 + k] = (double)gw[4 * (384 + n) + k];
        }
    }
    if (n >= N_NODES) return;

    const float4* zr = (const float4*)(z + (long)n * D_FEAT);
    double u0 = 0, u1 = 0, u2 = 0, u3 = 0;
    double v0 = 0, v1 = 0, v2 = 0, v3 = 0;
    for (int d4 = 0; d4 < D_FEAT / 4; ++d4) {
        float4 a = zr[d4];
        float av[4] = {a.x, a.y, a.z, a.w};
        #pragma unroll
        for (int j = 0; j < 4; ++j) {
            int d = d4 * 4 + j;
            const float4 g0 = *(const float4*)(gw + 4 * d);
            const float4 g1 = *(const float4*)(gw + 4 * (128 + d));
            double ad = (double)av[j];
            u0 += ad * (double)g0.x; u1 += ad * (double)g0.y;
            u2 += ad * (double)g0.z; u3 += ad * (double)g0.w;
            v0 += ad * (double)g1.x; v1 += ad * (double)g1.y;
            v2 += ad * (double)g1.z; v3 += ad * (double)g1.w;
        }
    }
    double* o = nodeTab + (long)n * 8;
    o[0] = u0; o[1] = u1; o[2] = u2; o[3] = u3;
    o[4] = v0; o[5] = v1; o[6] = v2; o[7] = v3;
}

// ---------------------------------------------------------------------------
// Phase 1: gate, 2 threads/edge. gwd staged in LDS (8 KB) so the per-lane
// (half-dependent) table reads are ds_read broadcasts, NOT per-lane VMEM —
// round-6 regression was the scalar->vector demotion of these loads.
// ---------------------------------------------------------------------------
__global__ __launch_bounds__(256) void gate_kernel(
    const float* __restrict__ z, const int* __restrict__ u, const int* __restrict__ v,
    const double* __restrict__ nodeTab, const double* __restrict__ gwd,
    const float* __restrict__ gb,
    float* __restrict__ probsum, unsigned* __restrict__ gcount,
    int* __restrict__ lists, float* __restrict__ pval)
{
    int tid  = threadIdx.x;
    int lane = tid & 63;
    int half = tid & 1;
    int e    = blockIdx.x * 128 + (tid >> 1);

    __shared__ double s_gwd[1024];     // [128][8]
    __shared__ float  s_ps[4];
    __shared__ int    s_cnt[4];
    __shared__ int    s_base[4];

    #pragma unroll
    for (int i = 0; i < 4; ++i)
        s_gwd[tid + i * 256] = gwd[tid + i * 256];
    if (tid < 4) { s_ps[tid] = 0.0f; s_cnt[tid] = 0; }
    __syncthreads();

    int ue = u[e], ve = v[e];
    const float4* zu4 = (const float4*)(z + (long)ue * D_FEAT) + half * 16;
    const float4* zv4 = (const float4*)(z + (long)ve * D_FEAT) + half * 16;
    const double* grb = s_gwd + (half << 9);   // half*64 rows * 8

    double la0 = 0, la1 = 0, la2 = 0, la3 = 0;
    double lm0 = 0, lm1 = 0, lm2 = 0, lm3 = 0;

    #pragma unroll 4
    for (int d4 = 0; d4 < 16; ++d4) {
        float4 a = zu4[d4];
        float4 b = zv4[d4];
        float av[4] = {a.x, a.y, a.z, a.w};
        float bv[4] = {b.x, b.y, b.z, b.w};
        #pragma unroll
        for (int j = 0; j < 4; ++j) {
            double ad = (double)fabsf(av[j] - bv[j]);
            double m  = (double)(av[j] * bv[j]);
            const double* gr = grb + (d4 * 4 + j) * 8;
            la0 += ad * gr[0]; lm0 += m * gr[4];
            la1 += ad * gr[1]; lm1 += m * gr[5];
            la2 += ad * gr[2]; lm2 += m * gr[6];
            la3 += ad * gr[3]; lm3 += m * gr[7];
        }
    }

    double l0 = la0 + lm0, l1 = la1 + lm1, l2 = la2 + lm2, l3 = la3 + lm3;
    if (half == 0) {
        const double* nu = nodeTab + (long)ue * 8;
        const double* nv = nodeTab + (long)ve * 8;
        l0 += (double)gb[0] + nu[0] + nv[4];
        l1 += (double)gb[1] + nu[1] + nv[5];
        l2 += (double)gb[2] + nu[2] + nv[6];
        l3 += (double)gb[3] + nu[3] + nv[7];
    }
    // combine the two halves; both lanes end with identical full logits
    l0 += __shfl_xor(l0, 1);
    l1 += __shfl_xor(l1, 1);
    l2 += __shfl_xor(l2, 1);
    l3 += __shfl_xor(l3, 1);

    // argmax on f64 logits (== argmax on probs)
    int sel = 0;
    double lb = l0;
    if (l1 > lb) { lb = l1; sel = 1; }
    if (l2 > lb) { lb = l2; sel = 2; }
    if (l3 > lb) { lb = l3; sel = 3; }

    // softmax in f32 (probs only feed pval / aux sums)
    float e0 = expf((float)(l0 - lb));
    float e1 = expf((float)(l1 - lb));
    float e2 = expf((float)(l2 - lb));
    float e3 = expf((float)(l3 - lb));
    float s   = e0 + e1 + e2 + e3;
    float inv = 1.0f / s;
    float p[4];
    p[0] = e0 * inv; p[1] = e1 * inv; p[2] = e2 * inv; p[3] = e3 * inv;
    float best = p[sel];

    // probsum: only even lanes contribute (avoid double count)
    float q0 = half ? 0.0f : p[0];
    float q1 = half ? 0.0f : p[1];
    float q2 = half ? 0.0f : p[2];
    float q3 = half ? 0.0f : p[3];
    #pragma unroll
    for (int off = 32; off > 0; off >>= 1) {
        q0 += __shfl_down(q0, off);
        q1 += __shfl_down(q1, off);
        q2 += __shfl_down(q2, off);
        q3 += __shfl_down(q3, off);
    }
    if (lane == 0) {
        atomicAdd(&s_ps[0], q0); atomicAdd(&s_ps[1], q1);
        atomicAdd(&s_ps[2], q2); atomicAdd(&s_ps[3], q3);
    }

    // compaction over even lanes only
    const unsigned long long EV = 0x5555555555555555ull;
    unsigned long long lt = (lane == 0) ? 0ull : ((~0ull) >> (64 - lane));
    int mywb = 0, myrank = 0;
    #pragma unroll
    for (int k = 0; k < 4; ++k) {
        unsigned long long mask = __ballot(sel == k) & EV;
        if (mask) {
            int leader = (int)__ffsll((unsigned long long)mask) - 1;
            int wb = 0;
            if (lane == leader) wb = atomicAdd(&s_cnt[k], (int)__popcll(mask));
            wb = __shfl(wb, leader);
            if (half == 0 && sel == k) { mywb = wb; myrank = (int)__popcll(mask & lt); }
        }
    }
    __syncthreads();

    if (tid < 4) {
        s_base[tid] = (int)atomicAdd(&gcount[tid], (unsigned)s_cnt[tid]);
        atomicAdd(&probsum[tid], s_ps[tid]);
    }
    __syncthreads();

    if (half == 0) {
        int pos = s_base[sel] + mywb + myrank;
        lists[sel * E_EDGES + pos] = e;
        pval[e] = best;
    }
}

// ---------------------------------------------------------------------------
// Phase 2: raw-z-in-LDS (round 15) + COMPILE-TIME K-loop (round 16). Rounds
// 8-15 pinned at 100-110 µs with no saturated pipe -> per-chunk chain
// (ds_read ~120cy -> cvt -> MFMA) serialized by the runtime-nc loop. Now the
// expert is templated: nc and chunk modes are compile-time, K-loop fully
// unrolled -> scheduler overlaps chunk c+1 loads with chunk c MFMAs.
// ---------------------------------------------------------------------------
#define ZPAD 132

template<int MODE>
__device__ __forceinline__ short8 build8(const float* pu, const float* pv)
{
    // MODE: 0=copy zu, 1=copy zv, 2=|zu-zv|, 3=zu*zv
    float o[8];
    if (MODE == 0) {
        float4 x0 = *(const float4*)pu, x1 = *(const float4*)(pu + 4);
        o[0]=x0.x; o[1]=x0.y; o[2]=x0.z; o[3]=x0.w;
        o[4]=x1.x; o[5]=x1.y; o[6]=x1.z; o[7]=x1.w;
    } else if (MODE == 1) {
        float4 y0 = *(const float4*)pv, y1 = *(const float4*)(pv + 4);
        o[0]=y0.x; o[1]=y0.y; o[2]=y0.z; o[3]=y0.w;
        o[4]=y1.x; o[5]=y1.y; o[6]=y1.z; o[7]=y1.w;
    } else if (MODE == 2) {
        float4 x0 = *(const float4*)pu, x1 = *(const float4*)(pu + 4);
        float4 y0 = *(const float4*)pv, y1 = *(const float4*)(pv + 4);
        o[0]=fabsf(x0.x-y0.x); o[1]=fabsf(x0.y-y0.y); o[2]=fabsf(x0.z-y0.z); o[3]=fabsf(x0.w-y0.w);
        o[4]=fabsf(x1.x-y1.x); o[5]=fabsf(x1.y-y1.y); o[6]=fabsf(x1.z-y1.z); o[7]=fabsf(x1.w-y1.w);
    } else {
        float4 x0 = *(const float4*)pu, x1 = *(const float4*)(pu + 4);
        float4 y0 = *(const float4*)pv, y1 = *(const float4*)(pv + 4);
        o[0]=x0.x*y0.x; o[1]=x0.y*y0.y; o[2]=x0.z*y0.z; o[3]=x0.w*y0.w;
        o[4]=x1.x*y1.x; o[5]=x1.y*y1.y; o[6]=x1.z*y1.z; o[7]=x1.w*y1.w;
    }
    short8 r;
    r[0]=(short)f2bf(o[0]); r[1]=(short)f2bf(o[1]);
    r[2]=(short)f2bf(o[2]); r[3]=(short)f2bf(o[3]);
    r[4]=(short)f2bf(o[4]); r[5]=(short)f2bf(o[5]);
    r[6]=(short)f2bf(o[6]); r[7]=(short)f2bf(o[7]);
    return r;
}

template<int C, int EX>
__device__ __forceinline__ void chunk_step(
    const float (*s_zr)[ZPAD], const short8* __restrict__ wB,
    int colA, int quad, int nb, floatx4 (&acc)[2][4])
{
    constexpr int kbase = C * 32;
    constexpr int MODE = (EX == 1) ? 2 : (EX == 2) ? 3 : (kbase >> 7);
    constexpr int roff = (EX == 1 || EX == 2) ? kbase : (kbase & 127);
    int kl = roff + (quad << 3);

    short8 a0 = build8<MODE>(&s_zr[colA][kl],      &s_zr[32 + colA][kl]);
    short8 a1 = build8<MODE>(&s_zr[16 + colA][kl], &s_zr[48 + colA][kl]);

    int g = (C << 2) + quad;
    short8 bf0 = wB[g * 256 + nb +  0];
    short8 bf1 = wB[g * 256 + nb + 16];
    short8 bf2 = wB[g * 256 + nb + 32];
    short8 bf3 = wB[g * 256 + nb + 48];

    acc[0][0] = __builtin_amdgcn_mfma_f32_16x16x32_bf16(a0, bf0, acc[0][0], 0, 0, 0);
    acc[1][0] = __builtin_amdgcn_mfma_f32_16x16x32_bf16(a1, bf0, acc[1][0], 0, 0, 0);
    acc[0][1] = __builtin_amdgcn_mfma_f32_16x16x32_bf16(a0, bf1, acc[0][1], 0, 0, 0);
    acc[1][1] = __builtin_amdgcn_mfma_f32_16x16x32_bf16(a1, bf1, acc[1][1], 0, 0, 0);
    acc[0][2] = __builtin_amdgcn_mfma_f32_16x16x32_bf16(a0, bf2, acc[0][2], 0, 0, 0);
    acc[1][2] = __builtin_amdgcn_mfma_f32_16x16x32_bf16(a1, bf2, acc[1][2], 0, 0, 0);
    acc[0][3] = __builtin_amdgcn_mfma_f32_16x16x32_bf16(a0, bf3, acc[0][3], 0, 0, 0);
    acc[1][3] = __builtin_amdgcn_mfma_f32_16x16x32_bf16(a1, bf3, acc[1][3], 0, 0, 0);
}

template<int EX, int NC>
__device__ __forceinline__ void run_kloop(
    const float (*s_zr)[ZPAD], const short8* __restrict__ wB,
    int colA, int quad, int nb, floatx4 (&acc)[2][4])
{
    // fully unrolled, compile-time chunk indices -> cross-chunk ILP
    if (NC > 0)  chunk_step<0,  EX>(s_zr, wB, colA, quad, nb, acc);
    if (NC > 1)  chunk_step<1,  EX>(s_zr, wB, colA, quad, nb, acc);
    if (NC > 2)  chunk_step<2,  EX>(s_zr, wB, colA, quad, nb, acc);
    if (NC > 3)  chunk_step<3,  EX>(s_zr, wB, colA, quad, nb, acc);
    if (NC > 4)  chunk_step<4,  EX>(s_zr, wB, colA, quad, nb, acc);
    if (NC > 5)  chunk_step<5,  EX>(s_zr, wB, colA, quad, nb, acc);
    if (NC > 6)  chunk_step<6,  EX>(s_zr, wB, colA, quad, nb, acc);
    if (NC > 7)  chunk_step<7,  EX>(s_zr, wB, colA, quad, nb, acc);
    if (NC > 8)  chunk_step<8,  EX>(s_zr, wB, colA, quad, nb, acc);
    if (NC > 9)  chunk_step<9,  EX>(s_zr, wB, colA, quad, nb, acc);
    if (NC > 10) chunk_step<10, EX>(s_zr, wB, colA, quad, nb, acc);
    if (NC > 11) chunk_step<11, EX>(s_zr, wB, colA, quad, nb, acc);
    if (NC > 12) chunk_step<12, EX>(s_zr, wB, colA, quad, nb, acc);
    if (NC > 13) chunk_step<13, EX>(s_zr, wB, colA, quad, nb, acc);
    if (NC > 14) chunk_step<14, EX>(s_zr, wB, colA, quad, nb, acc);
    if (NC > 15) chunk_step<15, EX>(s_zr, wB, colA, quad, nb, acc);
}

__global__ __launch_bounds__(256) void expert_kernel(
    const float* __restrict__ z, const int* __restrict__ u, const int* __restrict__ v,
    const unsigned short* __restrict__ w1b,
    const float* __restrict__ cb1, const float* __restrict__ cw2, const float* __restrict__ cb2,
    const float* __restrict__ db1, const float* __restrict__ dw2, const float* __restrict__ db2,
    const float* __restrict__ mb1, const float* __restrict__ mw2, const float* __restrict__ mb2,
    const float* __restrict__ ab1, const float* __restrict__ aw2, const float* __restrict__ ab2,
    const unsigned* __restrict__ gcount, const int* __restrict__ lists,
    const float* __restrict__ pval, const float* __restrict__ probsum,
    float* __restrict__ out)
{
    int tid = threadIdx.x;

    // aux loss (probsum final after gate): one thread, before any early-return
    if (blockIdx.x == 0 && blockIdx.y == 0 && tid == 0) {
        float a = 0.0f;
        #pragma unroll
        for (int k = 0; k < 4; ++k) {
            float mean = probsum[k] * (1.0f / (float)E_EDGES);
            a += mean * mean;
        }
        out[E_EDGES] = a * (float)NEXP;
    }

    int ex = blockIdx.y;
    const float *b1, *w2, *b2;
    int F, w1off;
    if (ex == 0)      { b1 = cb1; w2 = cw2; b2 = cb2; F = 256; w1off = W1B_OFF0; }
    else if (ex == 1) { b1 = db1; w2 = dw2; b2 = db2; F = 128; w1off = W1B_OFF1; }
    else if (ex == 2) { b1 = mb1; w2 = mw2; b2 = mb2; F = 128; w1off = W1B_OFF2; }
    else              { b1 = ab1; w2 = aw2; b2 = ab2; F = 512; w1off = W1B_OFF3; }

    unsigned cnt  = gcount[ex];
    unsigned tile = blockIdx.x * 32u;
    if (tile >= cnt) return;
    int nm = (int)min(32u, cnt - tile);

    __shared__ float s_zr[64][ZPAD];   // rows 0-31: z[u[e]], rows 32-63: z[v[e]]
    __shared__ int   s_e[32], s_u[32], s_v[32];
    __shared__ float s_pv[32];
    __shared__ float red[4][32];

    int wave = tid >> 6;
    int lane = tid & 63;
    int colA = lane & 15;
    int quad = lane >> 4;

    if (tid < 32) {
        int m = tid;
        int src = (m < nm) ? (int)(tile + m) : (int)tile;
        int e = lists[ex * E_EDGES + src];
        s_e[m] = e; s_u[m] = u[e]; s_v[m] = v[e]; s_pv[m] = pval[e];
    }
    __syncthreads();

    // ---- stage ALL raw z rows once (32 KB, coalesced 512B per 4 threads) ----
    {
        int r  = tid >> 2;               // 0..63
        int cs = (tid & 3) << 5;         // 0,32,64,96
        int node = (r < 32) ? s_u[r] : s_v[r - 32];
        const float4* src = (const float4*)(z + (long)node * D_FEAT + cs);
        float4* dst = (float4*)(&s_zr[r][cs]);
        #pragma unroll
        for (int i = 0; i < 8; ++i) dst[i] = src[i];
    }
    __syncthreads();

    const short8* wB = (const short8*)(w1b + w1off);

    floatx4 acc[2][4];
    #pragma unroll
    for (int t = 0; t < 2; ++t)
        #pragma unroll
        for (int j = 0; j < 4; ++j)
            acc[t][j] = (floatx4)(0.0f);

    int nb = wave * 64 + colA;

    if (ex == 0)      run_kloop<0, 8> (s_zr, wB, colA, quad, nb, acc);
    else if (ex == 1) run_kloop<1, 4> (s_zr, wB, colA, quad, nb, acc);
    else if (ex == 2) run_kloop<2, 4> (s_zr, wB, colA, quad, nb, acc);
    else              run_kloop<3, 16>(s_zr, wB, colA, quad, nb, acc);

    // epilogue: hidden = relu(acc + b1[h]); per-edge sum of hidden*w2[h]
    float b1v[4], w2v[4];
    #pragma unroll
    for (int j = 0; j < 4; ++j) {
        int h = wave * 64 + j * 16 + colA;
        b1v[j] = b1[h];
        w2v[j] = w2[h];
    }

    #pragma unroll
    for (int t = 0; t < 2; ++t) {
        #pragma unroll
        for (int r = 0; r < 4; ++r) {
            float s = 0.0f;
            #pragma unroll
            for (int j = 0; j < 4; ++j) {
                float h = acc[t][j][r] + b1v[j];
                s += fmaxf(h, 0.0f) * w2v[j];
            }
            s += __shfl_xor(s, 1);
            s += __shfl_xor(s, 2);
            s += __shfl_xor(s, 4);
            s += __shfl_xor(s, 8);
            if (colA == 0) {
                int m = 16 * t + quad * 4 + r;
                red[wave][m] = s;
            }
        }
    }
    __syncthreads();

    if (tid < 32) {
        int m = tid;
        if (m < nm) {
            float sc = red[0][m] + red[1][m] + red[2][m] + red[3][m] + b2[0];
            out[s_e[m]] = s_pv[m] * sc;
        }
    }
}

extern "C" void kernel_launch(void* const* d_in, const int* in_sizes, int n_in,
                              void* d_out, int out_size, void* d_ws, size_t ws_size,
                              hipStream_t stream)
{
    const float* z   = (const float*)d_in[0];
    const int*   u   = (const int*)d_in[1];
    const int*   v   = (const int*)d_in[2];
    const float* gw  = (const float*)d_in[3];
    const float* gb  = (const float*)d_in[4];
    const float* cw1 = (const float*)d_in[5];
    const float* cb1 = (const float*)d_in[6];
    const float* cw2 = (const float*)d_in[7];
    const float* cb2 = (const float*)d_in[8];
    const float* dw1 = (const float*)d_in[9];
    const float* db1 = (const float*)d_in[10];
    const float* dw2 = (const float*)d_in[11];
    const float* db2 = (const float*)d_in[12];
    const float* mw1 = (const float*)d_in[13];
    const float* mb1 = (const float*)d_in[14];
    const float* mw2 = (const float*)d_in[15];
    const float* mb2 = (const float*)d_in[16];
    const float* aw1 = (const float*)d_in[17];
    const float* ab1 = (const float*)d_in[18];
    const float* aw2 = (const float*)d_in[19];
    const float* ab2 = (const float*)d_in[20];

    float* out = (float*)d_out;
    char*  ws  = (char*)d_ws;

    float*          probsum = (float*)ws;
    unsigned*       gcount  = (unsigned*)(ws + 16);
    int*            lists   = (int*)(ws + 32);
    float*          pval    = (float*)(ws + 32 + 16ll * E_EDGES);
    unsigned short* w1b     = (unsigned short*)(ws + 32 + 20ll * E_EDGES);
    double*         gwd     = (double*)(ws + 32 + 20ll * E_EDGES + 524288);
    double*         nodeTab = (double*)(ws + 32 + 20ll * E_EDGES + 524288 + 8192);

    hipMemsetAsync(d_ws, 0, 32, stream);

    prep_kernel<<<1024 + (N_NODES + 255) / 256, 256, 0, stream>>>(
        cw1, dw1, mw1, aw1, w1b, z, gw, nodeTab, gwd);

    gate_kernel<<<E_EDGES / 128, 256, 0, stream>>>(z, u, v, nodeTab, gwd, gb,
                                                   probsum, gcount, lists, pval);

    dim3 g2(E_EDGES / 32, 4);
    expert_kernel<<<g2, 256, 0, stream>>>(z, u, v, w1b,
                                          cb1, cw2, cb2,
                                          db1, dw2, db2,
                                          mb1, mw2, mb2,
                                          ab1, aw2, ab2,
                                          gcount, lists, pval, probsum, out);
}

// Round 18
// 340.276 us; speedup vs baseline: 1.1659x; 1.1659x over previous
//
#include <hip/hip_runtime.h>
#include <hip/hip_bf16.h>
#include <math.h>

#define N_NODES 50000
#define E_EDGES 262144
#define D_FEAT  128
#define H_HID   256
#define NEXP    4

typedef __attribute__((ext_vector_type(8))) short  short8;
typedef __attribute__((ext_vector_type(4))) float  floatx4;

// ws layout:
//   [0..15]                      float probsum[4]
//   [16..31]                     unsigned count[4]
//   [32 .. 32+16*E)              int lists[4][E]
//   [+4*E)                       float pval[E]
//   [+512K)                      ushort w1b[262144]  (bf16, B-fragment-linear)
//   [+8K)                        double gwd[128*8]   (g2|g3 rows as f64)
//   [+3.2M)                      double nodeTab[N][8] (z.g0 | z.g1 in f64)
#define W1B_OFF0 0
#define W1B_OFF1 65536      // 256*256
#define W1B_OFF2 98304      // +128*256
#define W1B_OFF3 131072     // +128*256

__device__ __forceinline__ unsigned short f2bf(float f) {
    __hip_bfloat16 h = __float2bfloat16(f);       // RNE
    return *reinterpret_cast<unsigned short*>(&h);
}

// ---------------------------------------------------------------------------
// Phase 0 (merged): blocks 0..1023 convert W1 -> bf16 B-fragment layout;
// blocks 1024..1219 compute per-node linear gate contributions (f64) + gwd.
// ---------------------------------------------------------------------------
__global__ __launch_bounds__(256) void prep_kernel(
    const float* __restrict__ cw1, const float* __restrict__ dw1,
    const float* __restrict__ mw1, const float* __restrict__ aw1,
    unsigned short* __restrict__ w1b,
    const float* __restrict__ z, const float* __restrict__ gw,
    double* __restrict__ nodeTab, double* __restrict__ gwd)
{
    int bx  = blockIdx.x;
    int tid = threadIdx.x;

    if (bx < 1024) {
        // ---- conv: w1b[off + ((k>>3)*256 + n)*8 + (k&7)] = bf16(w1[k*256+n])
        int r = bx, n = tid;
        const float* src; int k, off;
        if (r < 256)      { src = cw1; k = r;       off = W1B_OFF0; }
        else if (r < 384) { src = dw1; k = r - 256; off = W1B_OFF1; }
        else if (r < 512) { src = mw1; k = r - 384; off = W1B_OFF2; }
        else              { src = aw1; k = r - 512; off = W1B_OFF3; }
        w1b[off + (((k >> 3) * 256 + n) << 3) + (k & 7)] = f2bf(src[k * 256 + n]);
        return;
    }

    int n = (bx - 1024) * 256 + tid;
    if (n < 128) {
        #pragma unroll
        for (int k = 0; k < 4; ++k) {
            gwd[n * 8 + k]     = (double)gw[4 * (256 + n) + k];
            gwd[n * 8 + 4 + k] = (double)gw[4 * (384 + n) + k];
        }
    }
    if (n >= N_NODES) return;

    const float4* zr = (const float4*)(z + (long)n * D_FEAT);
    double u0 = 0, u1 = 0, u2 = 0, u3 = 0;
    double v0 = 0, v1 = 0, v2 = 0, v3 = 0;
    for (int d4 = 0; d4 < D_FEAT / 4; ++d4) {
        float4 a = zr[d4];
        float av[4] = {a.x, a.y, a.z, a.w};
        #pragma unroll
        for (int j = 0; j < 4; ++j) {
            int d = d4 * 4 + j;
            const float4 g0 = *(const float4*)(gw + 4 * d);
            const float4 g1 = *(const float4*)(gw + 4 * (128 + d));
            double ad = (double)av[j];
            u0 += ad * (double)g0.x; u1 += ad * (double)g0.y;
            u2 += ad * (double)g0.z; u3 += ad * (double)g0.w;
            v0 += ad * (double)g1.x; v1 += ad * (double)g1.y;
            v2 += ad * (double)g1.z; v3 += ad * (double)g1.w;
        }
    }
    double* o = nodeTab + (long)n * 8;
    o[0] = u0; o[1] = u1; o[2] = u2; o[3] = u3;
    o[4] = v0; o[5] = v1; o[6] = v2; o[7] = v3;
}

// ---------------------------------------------------------------------------
// Phase 1: gate, FOUR threads/edge (quarter = tid&3, 32 features each).
// Round-17 pivot: gate is latency-bound (round-5 VALUBusy 12.9%, f64 floor
// ~9 µs) with a per-thread 512-FMA dependent chain at 2 thr/edge. 4 thr/edge
// halves the chain (256 FMA, 16 float4 loads) and doubles independent waves.
// gwd stays in LDS (round-6 lesson: keep table reads ds_read broadcasts).
// ---------------------------------------------------------------------------
__global__ __launch_bounds__(256) void gate_kernel(
    const float* __restrict__ z, const int* __restrict__ u, const int* __restrict__ v,
    const double* __restrict__ nodeTab, const double* __restrict__ gwd,
    const float* __restrict__ gb,
    float* __restrict__ probsum, unsigned* __restrict__ gcount,
    int* __restrict__ lists, float* __restrict__ pval)
{
    int tid     = threadIdx.x;
    int lane    = tid & 63;
    int quarter = tid & 3;
    int e       = blockIdx.x * 64 + (tid >> 2);

    __shared__ double s_gwd[1024];     // [128][8]
    __shared__ float  s_ps[4];
    __shared__ int    s_cnt[4];
    __shared__ int    s_base[4];

    #pragma unroll
    for (int i = 0; i < 4; ++i)
        s_gwd[tid + i * 256] = gwd[tid + i * 256];
    if (tid < 4) { s_ps[tid] = 0.0f; s_cnt[tid] = 0; }
    __syncthreads();

    int ue = u[e], ve = v[e];
    const float4* zu4 = (const float4*)(z + (long)ue * D_FEAT) + quarter * 8;
    const float4* zv4 = (const float4*)(z + (long)ve * D_FEAT) + quarter * 8;
    const double* grb = s_gwd + (quarter << 8);   // quarter*32 rows * 8

    double la0 = 0, la1 = 0, la2 = 0, la3 = 0;
    double lm0 = 0, lm1 = 0, lm2 = 0, lm3 = 0;

    #pragma unroll 4
    for (int d4 = 0; d4 < 8; ++d4) {
        float4 a = zu4[d4];
        float4 b = zv4[d4];
        float av[4] = {a.x, a.y, a.z, a.w};
        float bv[4] = {b.x, b.y, b.z, b.w};
        #pragma unroll
        for (int j = 0; j < 4; ++j) {
            double ad = (double)fabsf(av[j] - bv[j]);
            double m  = (double)(av[j] * bv[j]);
            const double* gr = grb + (d4 * 4 + j) * 8;
            la0 += ad * gr[0]; lm0 += m * gr[4];
            la1 += ad * gr[1]; lm1 += m * gr[5];
            la2 += ad * gr[2]; lm2 += m * gr[6];
            la3 += ad * gr[3]; lm3 += m * gr[7];
        }
    }

    double l0 = la0 + lm0, l1 = la1 + lm1, l2 = la2 + lm2, l3 = la3 + lm3;
    if (quarter == 0) {
        const double* nu = nodeTab + (long)ue * 8;
        const double* nv = nodeTab + (long)ve * 8;
        l0 += (double)gb[0] + nu[0] + nv[4];
        l1 += (double)gb[1] + nu[1] + nv[5];
        l2 += (double)gb[2] + nu[2] + nv[6];
        l3 += (double)gb[3] + nu[3] + nv[7];
    }
    // combine the four quarters; all 4 lanes end with identical full logits
    l0 += __shfl_xor(l0, 1); l0 += __shfl_xor(l0, 2);
    l1 += __shfl_xor(l1, 1); l1 += __shfl_xor(l1, 2);
    l2 += __shfl_xor(l2, 1); l2 += __shfl_xor(l2, 2);
    l3 += __shfl_xor(l3, 1); l3 += __shfl_xor(l3, 2);

    // argmax on f64 logits (== argmax on probs)
    int sel = 0;
    double lb = l0;
    if (l1 > lb) { lb = l1; sel = 1; }
    if (l2 > lb) { lb = l2; sel = 2; }
    if (l3 > lb) { lb = l3; sel = 3; }

    // softmax in f32 (probs only feed pval / aux sums)
    float e0 = expf((float)(l0 - lb));
    float e1 = expf((float)(l1 - lb));
    float e2 = expf((float)(l2 - lb));
    float e3 = expf((float)(l3 - lb));
    float s   = e0 + e1 + e2 + e3;
    float inv = 1.0f / s;
    float p[4];
    p[0] = e0 * inv; p[1] = e1 * inv; p[2] = e2 * inv; p[3] = e3 * inv;
    float best = p[sel];

    // probsum: only quarter==0 lanes contribute (avoid quadruple count)
    float q0 = quarter ? 0.0f : p[0];
    float q1 = quarter ? 0.0f : p[1];
    float q2 = quarter ? 0.0f : p[2];
    float q3 = quarter ? 0.0f : p[3];
    #pragma unroll
    for (int off = 32; off > 0; off >>= 1) {
        q0 += __shfl_down(q0, off);
        q1 += __shfl_down(q1, off);
        q2 += __shfl_down(q2, off);
        q3 += __shfl_down(q3, off);
    }
    if (lane == 0) {
        atomicAdd(&s_ps[0], q0); atomicAdd(&s_ps[1], q1);
        atomicAdd(&s_ps[2], q2); atomicAdd(&s_ps[3], q3);
    }

    // compaction over quarter==0 lanes only
    const unsigned long long EV = 0x1111111111111111ull;
    unsigned long long lt = (lane == 0) ? 0ull : ((~0ull) >> (64 - lane));
    int mywb = 0, myrank = 0;
    #pragma unroll
    for (int k = 0; k < 4; ++k) {
        unsigned long long mask = __ballot(sel == k) & EV;
        if (mask) {
            int leader = (int)__ffsll((unsigned long long)mask) - 1;
            int wb = 0;
            if (lane == leader) wb = atomicAdd(&s_cnt[k], (int)__popcll(mask));
            wb = __shfl(wb, leader);
            if (quarter == 0 && sel == k) { mywb = wb; myrank = (int)__popcll(mask & lt); }
        }
    }
    __syncthreads();

    if (tid < 4) {
        s_base[tid] = (int)atomicAdd(&gcount[tid], (unsigned)s_cnt[tid]);
        atomicAdd(&probsum[tid], s_ps[tid]);
    }
    __syncthreads();

    if (quarter == 0) {
        int pos = s_base[sel] + mywb + myrank;
        lists[sel * E_EDGES + pos] = e;
        pval[e] = best;
    }
}

// ---------------------------------------------------------------------------
// Phase 2: selected-expert MLP via bf16 MFMA, M=32 edge tile (ROUND-10 EXACT
// — best measured expert, 100.2 µs). Rounds 11-17 explored dbuf/raw-z/unroll
// variants: all 100-213 µs. acc[2][4]=32 AGPR + VGPR 44 -> 6 waves/SIMD.
// ---------------------------------------------------------------------------
#define FPAD 40   // row stride (elems): 80B rows keep b128 16B-aligned
#define PCHUNK 4  // k-chunks per staging pass

__device__ __forceinline__ float4 edge_feat4(int ex, const float* zu, const float* zv, int fg)
{
    if (ex == 0) {
        return (fg < 128) ? *(const float4*)(zu + fg)
                          : *(const float4*)(zv + fg - 128);
    } else if (ex == 1) {
        float4 a = *(const float4*)(zu + fg);
        float4 b = *(const float4*)(zv + fg);
        return make_float4(fabsf(a.x - b.x), fabsf(a.y - b.y),
                           fabsf(a.z - b.z), fabsf(a.w - b.w));
    } else if (ex == 2) {
        float4 a = *(const float4*)(zu + fg);
        float4 b = *(const float4*)(zv + fg);
        return make_float4(a.x * b.x, a.y * b.y, a.z * b.z, a.w * b.w);
    } else {
        if (fg < 128) {
            return *(const float4*)(zu + fg);
        } else if (fg < 256) {
            return *(const float4*)(zv + fg - 128);
        } else if (fg < 384) {
            float4 a = *(const float4*)(zu + fg - 256);
            float4 b = *(const float4*)(zv + fg - 256);
            return make_float4(fabsf(a.x - b.x), fabsf(a.y - b.y),
                               fabsf(a.z - b.z), fabsf(a.w - b.w));
        } else {
            float4 a = *(const float4*)(zu + fg - 384);
            float4 b = *(const float4*)(zv + fg - 384);
            return make_float4(a.x * b.x, a.y * b.y, a.z * b.z, a.w * b.w);
        }
    }
}

__global__ __launch_bounds__(256) void expert_kernel(
    const float* __restrict__ z, const int* __restrict__ u, const int* __restrict__ v,
    const unsigned short* __restrict__ w1b,
    const float* __restrict__ cb1, const float* __restrict__ cw2, const float* __restrict__ cb2,
    const float* __restrict__ db1, const float* __restrict__ dw2, const float* __restrict__ db2,
    const float* __restrict__ mb1, const float* __restrict__ mw2, const float* __restrict__ mb2,
    const float* __restrict__ ab1, const float* __restrict__ aw2, const float* __restrict__ ab2,
    const unsigned* __restrict__ gcount, const int* __restrict__ lists,
    const float* __restrict__ pval, const float* __restrict__ probsum,
    float* __restrict__ out)
{
    int tid = threadIdx.x;

    // aux loss (probsum final after gate): one thread, before any early-return
    if (blockIdx.x == 0 && blockIdx.y == 0 && tid == 0) {
        float a = 0.0f;
        #pragma unroll
        for (int k = 0; k < 4; ++k) {
            float mean = probsum[k] * (1.0f / (float)E_EDGES);
            a += mean * mean;
        }
        out[E_EDGES] = a * (float)NEXP;
    }

    int ex = blockIdx.y;
    const float *b1, *w2, *b2;
    int F, w1off;
    if (ex == 0)      { b1 = cb1; w2 = cw2; b2 = cb2; F = 256; w1off = W1B_OFF0; }
    else if (ex == 1) { b1 = db1; w2 = dw2; b2 = db2; F = 128; w1off = W1B_OFF1; }
    else if (ex == 2) { b1 = mb1; w2 = mw2; b2 = mb2; F = 128; w1off = W1B_OFF2; }
    else              { b1 = ab1; w2 = aw2; b2 = ab2; F = 512; w1off = W1B_OFF3; }

    unsigned cnt  = gcount[ex];
    unsigned tile = blockIdx.x * 32u;
    if (tile >= cnt) return;
    int nm = (int)min(32u, cnt - tile);

    __shared__ unsigned short featA[PCHUNK][32][FPAD];
    __shared__ int   s_e[32], s_u[32], s_v[32];
    __shared__ float s_pv[32];
    __shared__ float red[4][32];

    int wave = tid >> 6;
    int lane = tid & 63;
    int colA = lane & 15;
    int quad = lane >> 4;

    if (tid < 32) {
        int m = tid;
        int src = (m < nm) ? (int)(tile + m) : (int)tile;
        int e = lists[ex * E_EDGES + src];
        s_e[m] = e; s_u[m] = u[e]; s_v[m] = v[e]; s_pv[m] = pval[e];
    }
    __syncthreads();

    const short8* wB = (const short8*)(w1b + w1off);

    floatx4 acc[2][4];
    #pragma unroll
    for (int t = 0; t < 2; ++t)
        #pragma unroll
        for (int j = 0; j < 4; ++j)
            acc[t][j] = (floatx4)(0.0f);

    // staging indices: thread -> (edge fm, 4 consecutive k at fk)
    int fm = tid >> 3;           // 0..31
    int fk = (tid & 7) << 2;     // 0..28 step 4
    int nc = F >> 5;
    const float* zu = z + (long)s_u[fm] * D_FEAT;
    const float* zv = z + (long)s_v[fm] * D_FEAT;
    int nb = wave * 64 + colA;

    for (int c0 = 0; c0 < nc; c0 += PCHUNK) {
        int cend = min(PCHUNK, nc - c0);
        if (c0) __syncthreads();      // all waves done reading previous pass

        for (int cc = 0; cc < cend; ++cc) {
            int fg = (c0 + cc) * 32 + fk;
            float4 val = edge_feat4(ex, zu, zv, fg);
            ushort4 pk;
            pk.x = f2bf(val.x); pk.y = f2bf(val.y);
            pk.z = f2bf(val.z); pk.w = f2bf(val.w);
            *(ushort4*)(&featA[cc][fm][fk]) = pk;
        }
        __syncthreads();

        for (int cc = 0; cc < cend; ++cc) {
            int g = (c0 + cc) * 4 + quad;
            short8 bf0 = wB[g * 256 + nb +  0];
            short8 bf1 = wB[g * 256 + nb + 16];
            short8 bf2 = wB[g * 256 + nb + 32];
            short8 bf3 = wB[g * 256 + nb + 48];

            short8 a0 = *(const short8*)(&featA[cc][colA][quad * 8]);
            short8 a1 = *(const short8*)(&featA[cc][16 + colA][quad * 8]);

            acc[0][0] = __builtin_amdgcn_mfma_f32_16x16x32_bf16(a0, bf0, acc[0][0], 0, 0, 0);
            acc[1][0] = __builtin_amdgcn_mfma_f32_16x16x32_bf16(a1, bf0, acc[1][0], 0, 0, 0);
            acc[0][1] = __builtin_amdgcn_mfma_f32_16x16x32_bf16(a0, bf1, acc[0][1], 0, 0, 0);
            acc[1][1] = __builtin_amdgcn_mfma_f32_16x16x32_bf16(a1, bf1, acc[1][1], 0, 0, 0);
            acc[0][2] = __builtin_amdgcn_mfma_f32_16x16x32_bf16(a0, bf2, acc[0][2], 0, 0, 0);
            acc[1][2] = __builtin_amdgcn_mfma_f32_16x16x32_bf16(a1, bf2, acc[1][2], 0, 0, 0);
            acc[0][3] = __builtin_amdgcn_mfma_f32_16x16x32_bf16(a0, bf3, acc[0][3], 0, 0, 0);
            acc[1][3] = __builtin_amdgcn_mfma_f32_16x16x32_bf16(a1, bf3, acc[1][3], 0, 0, 0);
        }
    }

    // epilogue: hidden = relu(acc + b1[h]); per-edge sum of hidden*w2[h]
    float b1v[4], w2v[4];
    #pragma unroll
    for (int j = 0; j < 4; ++j) {
        int h = wave * 64 + j * 16 + colA;
        b1v[j] = b1[h];
        w2v[j] = w2[h];
    }

    #pragma unroll
    for (int t = 0; t < 2; ++t) {
        #pragma unroll
        for (int r = 0; r < 4; ++r) {
            float s = 0.0f;
            #pragma unroll
            for (int j = 0; j < 4; ++j) {
                float h = acc[t][j][r] + b1v[j];
                s += fmaxf(h, 0.0f) * w2v[j];
            }
            s += __shfl_xor(s, 1);
            s += __shfl_xor(s, 2);
            s += __shfl_xor(s, 4);
            s += __shfl_xor(s, 8);
            if (colA == 0) {
                int m = 16 * t + quad * 4 + r;
                red[wave][m] = s;
            }
        }
    }
    __syncthreads();

    if (tid < 32) {
        int m = tid;
        if (m < nm) {
            float sc = red[0][m] + red[1][m] + red[2][m] + red[3][m] + b2[0];
            out[s_e[m]] = s_pv[m] * sc;
        }
    }
}

extern "C" void kernel_launch(void* const* d_in, const int* in_sizes, int n_in,
                              void* d_out, int out_size, void* d_ws, size_t ws_size,
                              hipStream_t stream)
{
    const float* z   = (const float*)d_in[0];
    const int*   u   = (const int*)d_in[1];
    const int*   v   = (const int*)d_in[2];
    const float* gw  = (const float*)d_in[3];
    const float* gb  = (const float*)d_in[4];
    const float* cw1 = (const float*)d_in[5];
    const float* cb1 = (const float*)d_in[6];
    const float* cw2 = (const float*)d_in[7];
    const float* cb2 = (const float*)d_in[8];
    const float* dw1 = (const float*)d_in[9];
    const float* db1 = (const float*)d_in[10];
    const float* dw2 = (const float*)d_in[11];
    const float* db2 = (const float*)d_in[12];
    const float* mw1 = (const float*)d_in[13];
    const float* mb1 = (const float*)d_in[14];
    const float* mw2 = (const float*)d_in[15];
    const float* mb2 = (const float*)d_in[16];
    const float* aw1 = (const float*)d_in[17];
    const float* ab1 = (const float*)d_in[18];
    const float* aw2 = (const float*)d_in[19];
    const float* ab2 = (const float*)d_in[20];

    float* out = (float*)d_out;
    char*  ws  = (char*)d_ws;

    float*          probsum = (float*)ws;
    unsigned*       gcount  = (unsigned*)(ws + 16);
    int*            lists   = (int*)(ws + 32);
    float*          pval    = (float*)(ws + 32 + 16ll * E_EDGES);
    unsigned short* w1b     = (unsigned short*)(ws + 32 + 20ll * E_EDGES);
    double*         gwd     = (double*)(ws + 32 + 20ll * E_EDGES + 524288);
    double*         nodeTab = (double*)(ws + 32 + 20ll * E_EDGES + 524288 + 8192);

    hipMemsetAsync(d_ws, 0, 32, stream);

    prep_kernel<<<1024 + (N_NODES + 255) / 256, 256, 0, stream>>>(
        cw1, dw1, mw1, aw1, w1b, z, gw, nodeTab, gwd);

    gate_kernel<<<E_EDGES / 64, 256, 0, stream>>>(z, u, v, nodeTab, gwd, gb,
                                                  probsum, gcount, lists, pval);

    dim3 g2(E_EDGES / 32, 4);
    expert_kernel<<<g2, 256, 0, stream>>>(z, u, v, w1b,
                                          cb1, cw2, cb2,
                                          db1, dw2, db2,
                                          mb1, mw2, mb2,
                                          ab1, aw2, ab2,
                                          gcount, lists, pval, probsum, out);
}

// Round 19
// 293.839 us; speedup vs baseline: 1.3502x; 1.1580x over previous
//
#include <hip/hip_runtime.h>
#include <hip/hip_bf16.h>
#include <math.h>

#define N_NODES 50000
#define E_EDGES 262144
#define D_FEAT  128
#define H_HID   256
#define NEXP    4

typedef __attribute__((ext_vector_type(8))) short  short8;
typedef __attribute__((ext_vector_type(4))) float  floatx4;

// ws layout:
//   [0..15]                      float probsum[4]
//   [16..31]                     unsigned count[4]
//   [32 .. 32+16*E)              int lists[4][E]
//   [+4*E)                       float pval[E]
//   [+512K)                      ushort w1b[262144]  (bf16, B-fragment-linear)
//   [+8K)                        double gwd[128*8]   (g2|g3 rows as f64)
//   [+3.2M)                      double nodeTab[N][8] (z.g0 | z.g1 in f64)
#define W1B_OFF0 0
#define W1B_OFF1 65536      // 256*256
#define W1B_OFF2 98304      // +128*256
#define W1B_OFF3 131072     // +128*256

__device__ __forceinline__ unsigned short f2bf(float f) {
    __hip_bfloat16 h = __float2bfloat16(f);       // RNE
    return *reinterpret_cast<unsigned short*>(&h);
}

// ---------------------------------------------------------------------------
// Phase 0 (merged): blocks 0..1023 convert W1 -> bf16 B-fragment layout;
// blocks 1024..1219 compute per-node linear gate contributions (f64) + gwd.
// ---------------------------------------------------------------------------
__global__ __launch_bounds__(256) void prep_kernel(
    const float* __restrict__ cw1, const float* __restrict__ dw1,
    const float* __restrict__ mw1, const float* __restrict__ aw1,
    unsigned short* __restrict__ w1b,
    const float* __restrict__ z, const float* __restrict__ gw,
    double* __restrict__ nodeTab, double* __restrict__ gwd)
{
    int bx  = blockIdx.x;
    int tid = threadIdx.x;

    if (bx < 1024) {
        // ---- conv: w1b[off + ((k>>3)*256 + n)*8 + (k&7)] = bf16(w1[k*256+n])
        int r = bx, n = tid;
        const float* src; int k, off;
        if (r < 256)      { src = cw1; k = r;       off = W1B_OFF0; }
        else if (r < 384) { src = dw1; k = r - 256; off = W1B_OFF1; }
        else if (r < 512) { src = mw1; k = r - 384; off = W1B_OFF2; }
        else              { src = aw1; k = r - 512; off = W1B_OFF3; }
        w1b[off + (((k >> 3) * 256 + n) << 3) + (k & 7)] = f2bf(src[k * 256 + n]);
        return;
    }

    int n = (bx - 1024) * 256 + tid;
    if (n < 128) {
        #pragma unroll
        for (int k = 0; k < 4; ++k) {
            gwd[n * 8 + k]     = (double)gw[4 * (256 + n) + k];
            gwd[n * 8 + 4 + k] = (double)gw[4 * (384 + n) + k];
        }
    }
    if (n >= N_NODES) return;

    const float4* zr = (const float4*)(z + (long)n * D_FEAT);
    double u0 = 0, u1 = 0, u2 = 0, u3 = 0;
    double v0 = 0, v1 = 0, v2 = 0, v3 = 0;
    for (int d4 = 0; d4 < D_FEAT / 4; ++d4) {
        float4 a = zr[d4];
        float av[4] = {a.x, a.y, a.z, a.w};
        #pragma unroll
        for (int j = 0; j < 4; ++j) {
            int d = d4 * 4 + j;
            const float4 g0 = *(const float4*)(gw + 4 * d);
            const float4 g1 = *(const float4*)(gw + 4 * (128 + d));
            double ad = (double)av[j];
            u0 += ad * (double)g0.x; u1 += ad * (double)g0.y;
            u2 += ad * (double)g0.z; u3 += ad * (double)g0.w;
            v0 += ad * (double)g1.x; v1 += ad * (double)g1.y;
            v2 += ad * (double)g1.z; v3 += ad * (double)g1.w;
        }
    }
    double* o = nodeTab + (long)n * 8;
    o[0] = u0; o[1] = u1; o[2] = u2; o[3] = u3;
    o[4] = v0; o[5] = v1; o[6] = v2; o[7] = v3;
}

// ---------------------------------------------------------------------------
// Phase 1: gate, 2 threads/edge (ROUND-10 EXACT — best measured). gwd staged
// in LDS (8 KB): per-lane table reads are ds_read broadcasts at 2 addresses
// per wave (2-way aliasing = free, m136). 4-thr/edge variant (round 18)
// regressed: 4 addresses at stride 2048B = same bank -> 4-way conflict,
// SQ_LDS_BANK_CONFLICT 0 -> 2.5e7, gate 126 µs.
// ---------------------------------------------------------------------------
__global__ __launch_bounds__(256) void gate_kernel(
    const float* __restrict__ z, const int* __restrict__ u, const int* __restrict__ v,
    const double* __restrict__ nodeTab, const double* __restrict__ gwd,
    const float* __restrict__ gb,
    float* __restrict__ probsum, unsigned* __restrict__ gcount,
    int* __restrict__ lists, float* __restrict__ pval)
{
    int tid  = threadIdx.x;
    int lane = tid & 63;
    int half = tid & 1;
    int e    = blockIdx.x * 128 + (tid >> 1);

    __shared__ double s_gwd[1024];     // [128][8]
    __shared__ float  s_ps[4];
    __shared__ int    s_cnt[4];
    __shared__ int    s_base[4];

    #pragma unroll
    for (int i = 0; i < 4; ++i)
        s_gwd[tid + i * 256] = gwd[tid + i * 256];
    if (tid < 4) { s_ps[tid] = 0.0f; s_cnt[tid] = 0; }
    __syncthreads();

    int ue = u[e], ve = v[e];
    const float4* zu4 = (const float4*)(z + (long)ue * D_FEAT) + half * 16;
    const float4* zv4 = (const float4*)(z + (long)ve * D_FEAT) + half * 16;
    const double* grb = s_gwd + (half << 9);   // half*64 rows * 8

    double la0 = 0, la1 = 0, la2 = 0, la3 = 0;
    double lm0 = 0, lm1 = 0, lm2 = 0, lm3 = 0;

    #pragma unroll 4
    for (int d4 = 0; d4 < 16; ++d4) {
        float4 a = zu4[d4];
        float4 b = zv4[d4];
        float av[4] = {a.x, a.y, a.z, a.w};
        float bv[4] = {b.x, b.y, b.z, b.w};
        #pragma unroll
        for (int j = 0; j < 4; ++j) {
            double ad = (double)fabsf(av[j] - bv[j]);
            double m  = (double)(av[j] * bv[j]);
            const double* gr = grb + (d4 * 4 + j) * 8;
            la0 += ad * gr[0]; lm0 += m * gr[4];
            la1 += ad * gr[1]; lm1 += m * gr[5];
            la2 += ad * gr[2]; lm2 += m * gr[6];
            la3 += ad * gr[3]; lm3 += m * gr[7];
        }
    }

    double l0 = la0 + lm0, l1 = la1 + lm1, l2 = la2 + lm2, l3 = la3 + lm3;
    if (half == 0) {
        const double* nu = nodeTab + (long)ue * 8;
        const double* nv = nodeTab + (long)ve * 8;
        l0 += (double)gb[0] + nu[0] + nv[4];
        l1 += (double)gb[1] + nu[1] + nv[5];
        l2 += (double)gb[2] + nu[2] + nv[6];
        l3 += (double)gb[3] + nu[3] + nv[7];
    }
    // combine the two halves; both lanes end with identical full logits
    l0 += __shfl_xor(l0, 1);
    l1 += __shfl_xor(l1, 1);
    l2 += __shfl_xor(l2, 1);
    l3 += __shfl_xor(l3, 1);

    // argmax on f64 logits (== argmax on probs)
    int sel = 0;
    double lb = l0;
    if (l1 > lb) { lb = l1; sel = 1; }
    if (l2 > lb) { lb = l2; sel = 2; }
    if (l3 > lb) { lb = l3; sel = 3; }

    // softmax in f32 (probs only feed pval / aux sums)
    float e0 = expf((float)(l0 - lb));
    float e1 = expf((float)(l1 - lb));
    float e2 = expf((float)(l2 - lb));
    float e3 = expf((float)(l3 - lb));
    float s   = e0 + e1 + e2 + e3;
    float inv = 1.0f / s;
    float p[4];
    p[0] = e0 * inv; p[1] = e1 * inv; p[2] = e2 * inv; p[3] = e3 * inv;
    float best = p[sel];

    // probsum: only even lanes contribute (avoid double count)
    float q0 = half ? 0.0f : p[0];
    float q1 = half ? 0.0f : p[1];
    float q2 = half ? 0.0f : p[2];
    float q3 = half ? 0.0f : p[3];
    #pragma unroll
    for (int off = 32; off > 0; off >>= 1) {
        q0 += __shfl_down(q0, off);
        q1 += __shfl_down(q1, off);
        q2 += __shfl_down(q2, off);
        q3 += __shfl_down(q3, off);
    }
    if (lane == 0) {
        atomicAdd(&s_ps[0], q0); atomicAdd(&s_ps[1], q1);
        atomicAdd(&s_ps[2], q2); atomicAdd(&s_ps[3], q3);
    }

    // compaction over even lanes only
    const unsigned long long EV = 0x5555555555555555ull;
    unsigned long long lt = (lane == 0) ? 0ull : ((~0ull) >> (64 - lane));
    int mywb = 0, myrank = 0;
    #pragma unroll
    for (int k = 0; k < 4; ++k) {
        unsigned long long mask = __ballot(sel == k) & EV;
        if (mask) {
            int leader = (int)__ffsll((unsigned long long)mask) - 1;
            int wb = 0;
            if (lane == leader) wb = atomicAdd(&s_cnt[k], (int)__popcll(mask));
            wb = __shfl(wb, leader);
            if (half == 0 && sel == k) { mywb = wb; myrank = (int)__popcll(mask & lt); }
        }
    }
    __syncthreads();

    if (tid < 4) {
        s_base[tid] = (int)atomicAdd(&gcount[tid], (unsigned)s_cnt[tid]);
        atomicAdd(&probsum[tid], s_ps[tid]);
    }
    __syncthreads();

    if (half == 0) {
        int pos = s_base[sel] + mywb + myrank;
        lists[sel * E_EDGES + pos] = e;
        pval[e] = best;
    }
}

// ---------------------------------------------------------------------------
// Phase 2: selected-expert MLP via bf16 MFMA, M=32 edge tile (ROUND-10 EXACT
// — best measured expert, 100.2 µs). Rounds 11-17 explored dbuf/raw-z/unroll
// variants: all 100-213 µs. acc[2][4]=32 AGPR + VGPR 44 -> 6 waves/SIMD.
// ---------------------------------------------------------------------------
#define FPAD 40   // row stride (elems): 80B rows keep b128 16B-aligned
#define PCHUNK 4  // k-chunks per staging pass

__device__ __forceinline__ float4 edge_feat4(int ex, const float* zu, const float* zv, int fg)
{
    if (ex == 0) {
        return (fg < 128) ? *(const float4*)(zu + fg)
                          : *(const float4*)(zv + fg - 128);
    } else if (ex == 1) {
        float4 a = *(const float4*)(zu + fg);
        float4 b = *(const float4*)(zv + fg);
        return make_float4(fabsf(a.x - b.x), fabsf(a.y - b.y),
                           fabsf(a.z - b.z), fabsf(a.w - b.w));
    } else if (ex == 2) {
        float4 a = *(const float4*)(zu + fg);
        float4 b = *(const float4*)(zv + fg);
        return make_float4(a.x * b.x, a.y * b.y, a.z * b.z, a.w * b.w);
    } else {
        if (fg < 128) {
            return *(const float4*)(zu + fg);
        } else if (fg < 256) {
            return *(const float4*)(zv + fg - 128);
        } else if (fg < 384) {
            float4 a = *(const float4*)(zu + fg - 256);
            float4 b = *(const float4*)(zv + fg - 256);
            return make_float4(fabsf(a.x - b.x), fabsf(a.y - b.y),
                               fabsf(a.z - b.z), fabsf(a.w - b.w));
        } else {
            float4 a = *(const float4*)(zu + fg - 384);
            float4 b = *(const float4*)(zv + fg - 384);
            return make_float4(a.x * b.x, a.y * b.y, a.z * b.z, a.w * b.w);
        }
    }
}

__global__ __launch_bounds__(256) void expert_kernel(
    const float* __restrict__ z, const int* __restrict__ u, const int* __restrict__ v,
    const unsigned short* __restrict__ w1b,
    const float* __restrict__ cb1, const float* __restrict__ cw2, const float* __restrict__ cb2,
    const float* __restrict__ db1, const float* __restrict__ dw2, const float* __restrict__ db2,
    const float* __restrict__ mb1, const float* __restrict__ mw2, const float* __restrict__ mb2,
    const float* __restrict__ ab1, const float* __restrict__ aw2, const float* __restrict__ ab2,
    const unsigned* __restrict__ gcount, const int* __restrict__ lists,
    const float* __restrict__ pval, const float* __restrict__ probsum,
    float* __restrict__ out)
{
    int tid = threadIdx.x;

    // aux loss (probsum final after gate): one thread, before any early-return
    if (blockIdx.x == 0 && blockIdx.y == 0 && tid == 0) {
        float a = 0.0f;
        #pragma unroll
        for (int k = 0; k < 4; ++k) {
            float mean = probsum[k] * (1.0f / (float)E_EDGES);
            a += mean * mean;
        }
        out[E_EDGES] = a * (float)NEXP;
    }

    int ex = blockIdx.y;
    const float *b1, *w2, *b2;
    int F, w1off;
    if (ex == 0)      { b1 = cb1; w2 = cw2; b2 = cb2; F = 256; w1off = W1B_OFF0; }
    else if (ex == 1) { b1 = db1; w2 = dw2; b2 = db2; F = 128; w1off = W1B_OFF1; }
    else if (ex == 2) { b1 = mb1; w2 = mw2; b2 = mb2; F = 128; w1off = W1B_OFF2; }
    else              { b1 = ab1; w2 = aw2; b2 = ab2; F = 512; w1off = W1B_OFF3; }

    unsigned cnt  = gcount[ex];
    unsigned tile = blockIdx.x * 32u;
    if (tile >= cnt) return;
    int nm = (int)min(32u, cnt - tile);

    __shared__ unsigned short featA[PCHUNK][32][FPAD];
    __shared__ int   s_e[32], s_u[32], s_v[32];
    __shared__ float s_pv[32];
    __shared__ float red[4][32];

    int wave = tid >> 6;
    int lane = tid & 63;
    int colA = lane & 15;
    int quad = lane >> 4;

    if (tid < 32) {
        int m = tid;
        int src = (m < nm) ? (int)(tile + m) : (int)tile;
        int e = lists[ex * E_EDGES + src];
        s_e[m] = e; s_u[m] = u[e]; s_v[m] = v[e]; s_pv[m] = pval[e];
    }
    __syncthreads();

    const short8* wB = (const short8*)(w1b + w1off);

    floatx4 acc[2][4];
    #pragma unroll
    for (int t = 0; t < 2; ++t)
        #pragma unroll
        for (int j = 0; j < 4; ++j)
            acc[t][j] = (floatx4)(0.0f);

    // staging indices: thread -> (edge fm, 4 consecutive k at fk)
    int fm = tid >> 3;           // 0..31
    int fk = (tid & 7) << 2;     // 0..28 step 4
    int nc = F >> 5;
    const float* zu = z + (long)s_u[fm] * D_FEAT;
    const float* zv = z + (long)s_v[fm] * D_FEAT;
    int nb = wave * 64 + colA;

    for (int c0 = 0; c0 < nc; c0 += PCHUNK) {
        int cend = min(PCHUNK, nc - c0);
        if (c0) __syncthreads();      // all waves done reading previous pass

        for (int cc = 0; cc < cend; ++cc) {
            int fg = (c0 + cc) * 32 + fk;
            float4 val = edge_feat4(ex, zu, zv, fg);
            ushort4 pk;
            pk.x = f2bf(val.x); pk.y = f2bf(val.y);
            pk.z = f2bf(val.z); pk.w = f2bf(val.w);
            *(ushort4*)(&featA[cc][fm][fk]) = pk;
        }
        __syncthreads();

        for (int cc = 0; cc < cend; ++cc) {
            int g = (c0 + cc) * 4 + quad;
            short8 bf0 = wB[g * 256 + nb +  0];
            short8 bf1 = wB[g * 256 + nb + 16];
            short8 bf2 = wB[g * 256 + nb + 32];
            short8 bf3 = wB[g * 256 + nb + 48];

            short8 a0 = *(const short8*)(&featA[cc][colA][quad * 8]);
            short8 a1 = *(const short8*)(&featA[cc][16 + colA][quad * 8]);

            acc[0][0] = __builtin_amdgcn_mfma_f32_16x16x32_bf16(a0, bf0, acc[0][0], 0, 0, 0);
            acc[1][0] = __builtin_amdgcn_mfma_f32_16x16x32_bf16(a1, bf0, acc[1][0], 0, 0, 0);
            acc[0][1] = __builtin_amdgcn_mfma_f32_16x16x32_bf16(a0, bf1, acc[0][1], 0, 0, 0);
            acc[1][1] = __builtin_amdgcn_mfma_f32_16x16x32_bf16(a1, bf1, acc[1][1], 0, 0, 0);
            acc[0][2] = __builtin_amdgcn_mfma_f32_16x16x32_bf16(a0, bf2, acc[0][2], 0, 0, 0);
            acc[1][2] = __builtin_amdgcn_mfma_f32_16x16x32_bf16(a1, bf2, acc[1][2], 0, 0, 0);
            acc[0][3] = __builtin_amdgcn_mfma_f32_16x16x32_bf16(a0, bf3, acc[0][3], 0, 0, 0);
            acc[1][3] = __builtin_amdgcn_mfma_f32_16x16x32_bf16(a1, bf3, acc[1][3], 0, 0, 0);
        }
    }

    // epilogue: hidden = relu(acc + b1[h]); per-edge sum of hidden*w2[h]
    float b1v[4], w2v[4];
    #pragma unroll
    for (int j = 0; j < 4; ++j) {
        int h = wave * 64 + j * 16 + colA;
        b1v[j] = b1[h];
        w2v[j] = w2[h];
    }

    #pragma unroll
    for (int t = 0; t < 2; ++t) {
        #pragma unroll
        for (int r = 0; r < 4; ++r) {
            float s = 0.0f;
            #pragma unroll
            for (int j = 0; j < 4; ++j) {
                float h = acc[t][j][r] + b1v[j];
                s += fmaxf(h, 0.0f) * w2v[j];
            }
            s += __shfl_xor(s, 1);
            s += __shfl_xor(s, 2);
            s += __shfl_xor(s, 4);
            s += __shfl_xor(s, 8);
            if (colA == 0) {
                int m = 16 * t + quad * 4 + r;
                red[wave][m] = s;
            }
        }
    }
    __syncthreads();

    if (tid < 32) {
        int m = tid;
        if (m < nm) {
            float sc = red[0][m] + red[1][m] + red[2][m] + red[3][m] + b2[0];
            out[s_e[m]] = s_pv[m] * sc;
        }
    }
}

extern "C" void kernel_launch(void* const* d_in, const int* in_sizes, int n_in,
                              void* d_out, int out_size, void* d_ws, size_t ws_size,
                              hipStream_t stream)
{
    const float* z   = (const float*)d_in[0];
    const int*   u   = (const int*)d_in[1];
    const int*   v   = (const int*)d_in[2];
    const float* gw  = (const float*)d_in[3];
    const float* gb  = (const float*)d_in[4];
    const float* cw1 = (const float*)d_in[5];
    const float* cb1 = (const float*)d_in[6];
    const float* cw2 = (const float*)d_in[7];
    const float* cb2 = (const float*)d_in[8];
    const float* dw1 = (const float*)d_in[9];
    const float* db1 = (const float*)d_in[10];
    const float* dw2 = (const float*)d_in[11];
    const float* db2 = (const float*)d_in[12];
    const float* mw1 = (const float*)d_in[13];
    const float* mb1 = (const float*)d_in[14];
    const float* mw2 = (const float*)d_in[15];
    const float* mb2 = (const float*)d_in[16];
    const float* aw1 = (const float*)d_in[17];
    const float* ab1 = (const float*)d_in[18];
    const float* aw2 = (const float*)d_in[19];
    const float* ab2 = (const float*)d_in[20];

    float* out = (float*)d_out;
    char*  ws  = (char*)d_ws;

    float*          probsum = (float*)ws;
    unsigned*       gcount  = (unsigned*)(ws + 16);
    int*            lists   = (int*)(ws + 32);
    float*          pval    = (float*)(ws + 32 + 16ll * E_EDGES);
    unsigned short* w1b     = (unsigned short*)(ws + 32 + 20ll * E_EDGES);
    double*         gwd     = (double*)(ws + 32 + 20ll * E_EDGES + 524288);
    double*         nodeTab = (double*)(ws + 32 + 20ll * E_EDGES + 524288 + 8192);

    hipMemsetAsync(d_ws, 0, 32, stream);

    prep_kernel<<<1024 + (N_NODES + 255) / 256, 256, 0, stream>>>(
        cw1, dw1, mw1, aw1, w1b, z, gw, nodeTab, gwd);

    gate_kernel<<<E_EDGES / 128, 256, 0, stream>>>(z, u, v, nodeTab, gwd, gb,
                                                   probsum, gcount, lists, pval);

    dim3 g2(E_EDGES / 32, 4);
    expert_kernel<<<g2, 256, 0, stream>>>(z, u, v, w1b,
                                          cb1, cw2, cb2,
                                          db1, dw2, db2,
                                          mb1, mw2, mb2,
                                          ab1, aw2, ab2,
                                          gcount, lists, pval, probsum, out);
}

// Round 23
// 287.971 us; speedup vs baseline: 1.3777x; 1.0204x over previous
//
#include <hip/hip_runtime.h>
#include <hip/hip_bf16.h>
#include <math.h>

#define N_NODES 50000
#define E_EDGES 262144
#define D_FEAT  128
#define H_HID   256
#define NEXP    4

typedef __attribute__((ext_vector_type(8))) short  short8;
typedef __attribute__((ext_vector_type(4))) float  floatx4;

// ws layout:
//   [0..15]                      float probsum[4]
//   [16..31]                     unsigned count[4]
//   [32 .. 32+16*E)              int lists[4][E]
//   [+4*E)                       float pval[E]
//   [+512K)                      ushort w1b[262144]  (bf16, B-fragment-linear)
//   [+8K)                        double gwd[128*8]   (g2|g3 rows as f64)
//   [+3.2M)                      double nodeTab[N][8] (z.g0 | z.g1 in f64)
#define W1B_OFF0 0
#define W1B_OFF1 65536      // 256*256
#define W1B_OFF2 98304      // +128*256
#define W1B_OFF3 131072     // +128*256

__device__ __forceinline__ unsigned short f2bf(float f) {
    __hip_bfloat16 h = __float2bfloat16(f);       // RNE
    return *reinterpret_cast<unsigned short*>(&h);
}

// ---------------------------------------------------------------------------
// Phase 0 (merged): blocks 0..1023 convert W1 -> bf16 B-fragment layout;
// blocks 1024..1219 compute per-node linear gate contributions (f64) + gwd.
// ---------------------------------------------------------------------------
__global__ __launch_bounds__(256) void prep_kernel(
    const float* __restrict__ cw1, const float* __restrict__ dw1,
    const float* __restrict__ mw1, const float* __restrict__ aw1,
    unsigned short* __restrict__ w1b,
    const float* __restrict__ z, const float* __restrict__ gw,
    double* __restrict__ nodeTab, double* __restrict__ gwd)
{
    int bx  = blockIdx.x;
    int tid = threadIdx.x;

    if (bx < 1024) {
        // ---- conv: w1b[off + ((k>>3)*256 + n)*8 + (k&7)] = bf16(w1[k*256+n])
        int r = bx, n = tid;
        const float* src; int k, off;
        if (r < 256)      { src = cw1; k = r;       off = W1B_OFF0; }
        else if (r < 384) { src = dw1; k = r - 256; off = W1B_OFF1; }
        else if (r < 512) { src = mw1; k = r - 384; off = W1B_OFF2; }
        else              { src = aw1; k = r - 512; off = W1B_OFF3; }
        w1b[off + (((k >> 3) * 256 + n) << 3) + (k & 7)] = f2bf(src[k * 256 + n]);
        return;
    }

    int n = (bx - 1024) * 256 + tid;
    if (n < 128) {
        #pragma unroll
        for (int k = 0; k < 4; ++k) {
            gwd[n * 8 + k]     = (double)gw[4 * (256 + n) + k];
            gwd[n * 8 + 4 + k] = (double)gw[4 * (384 + n) + k];
        }
    }
    if (n >= N_NODES) return;

    const float4* zr = (const float4*)(z + (long)n * D_FEAT);
    double u0 = 0, u1 = 0, u2 = 0, u3 = 0;
    double v0 = 0, v1 = 0, v2 = 0, v3 = 0;
    for (int d4 = 0; d4 < D_FEAT / 4; ++d4) {
        float4 a = zr[d4];
        float av[4] = {a.x, a.y, a.z, a.w};
        #pragma unroll
        for (int j = 0; j < 4; ++j) {
            int d = d4 * 4 + j;
            const float4 g0 = *(const float4*)(gw + 4 * d);
            const float4 g1 = *(const float4*)(gw + 4 * (128 + d));
            double ad = (double)av[j];
            u0 += ad * (double)g0.x; u1 += ad * (double)g0.y;
            u2 += ad * (double)g0.z; u3 += ad * (double)g0.w;
            v0 += ad * (double)g1.x; v1 += ad * (double)g1.y;
            v2 += ad * (double)g1.z; v3 += ad * (double)g1.w;
        }
    }
    double* o = nodeTab + (long)n * 8;
    o[0] = u0; o[1] = u1; o[2] = u2; o[3] = u3;
    o[4] = v0; o[5] = v1; o[6] = v2; o[7] = v3;
}

// ---------------------------------------------------------------------------
// Phase 1: gate, 2 threads/edge (ROUND-10 EXACT — best measured). gwd staged
// in LDS (8 KB): per-lane table reads are ds_read broadcasts at 2 addresses
// per wave (2-way aliasing = free, m136). 4-thr/edge variant (round 18)
// regressed: 4 addresses at stride 2048B = same bank -> 4-way conflict.
// ---------------------------------------------------------------------------
__global__ __launch_bounds__(256) void gate_kernel(
    const float* __restrict__ z, const int* __restrict__ u, const int* __restrict__ v,
    const double* __restrict__ nodeTab, const double* __restrict__ gwd,
    const float* __restrict__ gb,
    float* __restrict__ probsum, unsigned* __restrict__ gcount,
    int* __restrict__ lists, float* __restrict__ pval)
{
    int tid  = threadIdx.x;
    int lane = tid & 63;
    int half = tid & 1;
    int e    = blockIdx.x * 128 + (tid >> 1);

    __shared__ double s_gwd[1024];     // [128][8]
    __shared__ float  s_ps[4];
    __shared__ int    s_cnt[4];
    __shared__ int    s_base[4];

    #pragma unroll
    for (int i = 0; i < 4; ++i)
        s_gwd[tid + i * 256] = gwd[tid + i * 256];
    if (tid < 4) { s_ps[tid] = 0.0f; s_cnt[tid] = 0; }
    __syncthreads();

    int ue = u[e], ve = v[e];
    const float4* zu4 = (const float4*)(z + (long)ue * D_FEAT) + half * 16;
    const float4* zv4 = (const float4*)(z + (long)ve * D_FEAT) + half * 16;
    const double* grb = s_gwd + (half << 9);   // half*64 rows * 8

    double la0 = 0, la1 = 0, la2 = 0, la3 = 0;
    double lm0 = 0, lm1 = 0, lm2 = 0, lm3 = 0;

    #pragma unroll 4
    for (int d4 = 0; d4 < 16; ++d4) {
        float4 a = zu4[d4];
        float4 b = zv4[d4];
        float av[4] = {a.x, a.y, a.z, a.w};
        float bv[4] = {b.x, b.y, b.z, b.w};
        #pragma unroll
        for (int j = 0; j < 4; ++j) {
            double ad = (double)fabsf(av[j] - bv[j]);
            double m  = (double)(av[j] * bv[j]);
            const double* gr = grb + (d4 * 4 + j) * 8;
            la0 += ad * gr[0]; lm0 += m * gr[4];
            la1 += ad * gr[1]; lm1 += m * gr[5];
            la2 += ad * gr[2]; lm2 += m * gr[6];
            la3 += ad * gr[3]; lm3 += m * gr[7];
        }
    }

    double l0 = la0 + lm0, l1 = la1 + lm1, l2 = la2 + lm2, l3 = la3 + lm3;
    if (half == 0) {
        const double* nu = nodeTab + (long)ue * 8;
        const double* nv = nodeTab + (long)ve * 8;
        l0 += (double)gb[0] + nu[0] + nv[4];
        l1 += (double)gb[1] + nu[1] + nv[5];
        l2 += (double)gb[2] + nu[2] + nv[6];
        l3 += (double)gb[3] + nu[3] + nv[7];
    }
    // combine the two halves; both lanes end with identical full logits
    l0 += __shfl_xor(l0, 1);
    l1 += __shfl_xor(l1, 1);
    l2 += __shfl_xor(l2, 1);
    l3 += __shfl_xor(l3, 1);

    // argmax on f64 logits (== argmax on probs)
    int sel = 0;
    double lb = l0;
    if (l1 > lb) { lb = l1; sel = 1; }
    if (l2 > lb) { lb = l2; sel = 2; }
    if (l3 > lb) { lb = l3; sel = 3; }

    // softmax in f32 (probs only feed pval / aux sums)
    float e0 = expf((float)(l0 - lb));
    float e1 = expf((float)(l1 - lb));
    float e2 = expf((float)(l2 - lb));
    float e3 = expf((float)(l3 - lb));
    float s   = e0 + e1 + e2 + e3;
    float inv = 1.0f / s;
    float p[4];
    p[0] = e0 * inv; p[1] = e1 * inv; p[2] = e2 * inv; p[3] = e3 * inv;
    float best = p[sel];

    // probsum: only even lanes contribute (avoid double count)
    float q0 = half ? 0.0f : p[0];
    float q1 = half ? 0.0f : p[1];
    float q2 = half ? 0.0f : p[2];
    float q3 = half ? 0.0f : p[3];
    #pragma unroll
    for (int off = 32; off > 0; off >>= 1) {
        q0 += __shfl_down(q0, off);
        q1 += __shfl_down(q1, off);
        q2 += __shfl_down(q2, off);
        q3 += __shfl_down(q3, off);
    }
    if (lane == 0) {
        atomicAdd(&s_ps[0], q0); atomicAdd(&s_ps[1], q1);
        atomicAdd(&s_ps[2], q2); atomicAdd(&s_ps[3], q3);
    }

    // compaction over even lanes only
    const unsigned long long EV = 0x5555555555555555ull;
    unsigned long long lt = (lane == 0) ? 0ull : ((~0ull) >> (64 - lane));
    int mywb = 0, myrank = 0;
    #pragma unroll
    for (int k = 0; k < 4; ++k) {
        unsigned long long mask = __ballot(sel == k) & EV;
        if (mask) {
            int leader = (int)__ffsll((unsigned long long)mask) - 1;
            int wb = 0;
            if (lane == leader) wb = atomicAdd(&s_cnt[k], (int)__popcll(mask));
            wb = __shfl(wb, leader);
            if (half == 0 && sel == k) { mywb = wb; myrank = (int)__popcll(mask & lt); }
        }
    }
    __syncthreads();

    if (tid < 4) {
        s_base[tid] = (int)atomicAdd(&gcount[tid], (unsigned)s_cnt[tid]);
        atomicAdd(&probsum[tid], s_ps[tid]);
    }
    __syncthreads();

    if (half == 0) {
        int pos = s_base[sel] + mywb + myrank;
        lists[sel * E_EDGES + pos] = e;
        pval[e] = best;
    }
}

// ---------------------------------------------------------------------------
// Phase 2: selected-expert MLP via bf16 MFMA, M=32 edge tile (round-10 body).
// Round 20: LONGEST-JOB-FIRST y->expert remap. Grid is x-fastest, so with
// ex==blockIdx.y the F=512 expert's blocks (4x work) dispatched LAST ->
// pure-heavy tail drains at low CU utilization (avg occupancy 48% vs 75% cap).
// ex = (y+3)&3 runs F=512 first; F=128 experts backfill the tail.
// ---------------------------------------------------------------------------
#define FPAD 40   // row stride (elems): 80B rows keep b128 16B-aligned
#define PCHUNK 4  // k-chunks per staging pass

__device__ __forceinline__ float4 edge_feat4(int ex, const float* zu, const float* zv, int fg)
{
    if (ex == 0) {
        return (fg < 128) ? *(const float4*)(zu + fg)
                          : *(const float4*)(zv + fg - 128);
    } else if (ex == 1) {
        float4 a = *(const float4*)(zu + fg);
        float4 b = *(const float4*)(zv + fg);
        return make_float4(fabsf(a.x - b.x), fabsf(a.y - b.y),
                           fabsf(a.z - b.z), fabsf(a.w - b.w));
    } else if (ex == 2) {
        float4 a = *(const float4*)(zu + fg);
        float4 b = *(const float4*)(zv + fg);
        return make_float4(a.x * b.x, a.y * b.y, a.z * b.z, a.w * b.w);
    } else {
        if (fg < 128) {
            return *(const float4*)(zu + fg);
        } else if (fg < 256) {
            return *(const float4*)(zv + fg - 128);
        } else if (fg < 384) {
            float4 a = *(const float4*)(zu + fg - 256);
            float4 b = *(const float4*)(zv + fg - 256);
            return make_float4(fabsf(a.x - b.x), fabsf(a.y - b.y),
                               fabsf(a.z - b.z), fabsf(a.w - b.w));
        } else {
            float4 a = *(const float4*)(zu + fg - 384);
            float4 b = *(const float4*)(zv + fg - 384);
            return make_float4(a.x * b.x, a.y * b.y, a.z * b.z, a.w * b.w);
        }
    }
}

__global__ __launch_bounds__(256) void expert_kernel(
    const float* __restrict__ z, const int* __restrict__ u, const int* __restrict__ v,
    const unsigned short* __restrict__ w1b,
    const float* __restrict__ cb1, const float* __restrict__ cw2, const float* __restrict__ cb2,
    const float* __restrict__ db1, const float* __restrict__ dw2, const float* __restrict__ db2,
    const float* __restrict__ mb1, const float* __restrict__ mw2, const float* __restrict__ mb2,
    const float* __restrict__ ab1, const float* __restrict__ aw2, const float* __restrict__ ab2,
    const unsigned* __restrict__ gcount, const int* __restrict__ lists,
    const float* __restrict__ pval, const float* __restrict__ probsum,
    float* __restrict__ out)
{
    int tid = threadIdx.x;

    // aux loss (probsum final after gate): one thread, before any early-return
    if (blockIdx.x == 0 && blockIdx.y == 0 && tid == 0) {
        float a = 0.0f;
        #pragma unroll
        for (int k = 0; k < 4; ++k) {
            float mean = probsum[k] * (1.0f / (float)E_EDGES);
            a += mean * mean;
        }
        out[E_EDGES] = a * (float)NEXP;
    }

    // longest-job-first: y=0 -> expert 3 (F=512), y=1 -> 0, y=2 -> 1, y=3 -> 2
    int ex = ((int)blockIdx.y + 3) & 3;
    const float *b1, *w2, *b2;
    int F, w1off;
    if (ex == 0)      { b1 = cb1; w2 = cw2; b2 = cb2; F = 256; w1off = W1B_OFF0; }
    else if (ex == 1) { b1 = db1; w2 = dw2; b2 = db2; F = 128; w1off = W1B_OFF1; }
    else if (ex == 2) { b1 = mb1; w2 = mw2; b2 = mb2; F = 128; w1off = W1B_OFF2; }
    else              { b1 = ab1; w2 = aw2; b2 = ab2; F = 512; w1off = W1B_OFF3; }

    unsigned cnt  = gcount[ex];
    unsigned tile = blockIdx.x * 32u;
    if (tile >= cnt) return;
    int nm = (int)min(32u, cnt - tile);

    __shared__ unsigned short featA[PCHUNK][32][FPAD];
    __shared__ int   s_e[32], s_u[32], s_v[32];
    __shared__ float s_pv[32];
    __shared__ float red[4][32];

    int wave = tid >> 6;
    int lane = tid & 63;
    int colA = lane & 15;
    int quad = lane >> 4;

    if (tid < 32) {
        int m = tid;
        int src = (m < nm) ? (int)(tile + m) : (int)tile;
        int e = lists[ex * E_EDGES + src];
        s_e[m] = e; s_u[m] = u[e]; s_v[m] = v[e]; s_pv[m] = pval[e];
    }
    __syncthreads();

    const short8* wB = (const short8*)(w1b + w1off);

    floatx4 acc[2][4];
    #pragma unroll
    for (int t = 0; t < 2; ++t)
        #pragma unroll
        for (int j = 0; j < 4; ++j)
            acc[t][j] = (floatx4)(0.0f);

    // staging indices: thread -> (edge fm, 4 consecutive k at fk)
    int fm = tid >> 3;           // 0..31
    int fk = (tid & 7) << 2;     // 0..28 step 4
    int nc = F >> 5;
    const float* zu = z + (long)s_u[fm] * D_FEAT;
    const float* zv = z + (long)s_v[fm] * D_FEAT;
    int nb = wave * 64 + colA;

    for (int c0 = 0; c0 < nc; c0 += PCHUNK) {
        int cend = min(PCHUNK, nc - c0);
        if (c0) __syncthreads();      // all waves done reading previous pass

        for (int cc = 0; cc < cend; ++cc) {
            int fg = (c0 + cc) * 32 + fk;
            float4 val = edge_feat4(ex, zu, zv, fg);
            ushort4 pk;
            pk.x = f2bf(val.x); pk.y = f2bf(val.y);
            pk.z = f2bf(val.z); pk.w = f2bf(val.w);
            *(ushort4*)(&featA[cc][fm][fk]) = pk;
        }
        __syncthreads();

        for (int cc = 0; cc < cend; ++cc) {
            int g = (c0 + cc) * 4 + quad;
            short8 bf0 = wB[g * 256 + nb +  0];
            short8 bf1 = wB[g * 256 + nb + 16];
            short8 bf2 = wB[g * 256 + nb + 32];
            short8 bf3 = wB[g * 256 + nb + 48];

            short8 a0 = *(const short8*)(&featA[cc][colA][quad * 8]);
            short8 a1 = *(const short8*)(&featA[cc][16 + colA][quad * 8]);

            acc[0][0] = __builtin_amdgcn_mfma_f32_16x16x32_bf16(a0, bf0, acc[0][0], 0, 0, 0);
            acc[1][0] = __builtin_amdgcn_mfma_f32_16x16x32_bf16(a1, bf0, acc[1][0], 0, 0, 0);
            acc[0][1] = __builtin_amdgcn_mfma_f32_16x16x32_bf16(a0, bf1, acc[0][1], 0, 0, 0);
            acc[1][1] = __builtin_amdgcn_mfma_f32_16x16x32_bf16(a1, bf1, acc[1][1], 0, 0, 0);
            acc[0][2] = __builtin_amdgcn_mfma_f32_16x16x32_bf16(a0, bf2, acc[0][2], 0, 0, 0);
            acc[1][2] = __builtin_amdgcn_mfma_f32_16x16x32_bf16(a1, bf2, acc[1][2], 0, 0, 0);
            acc[0][3] = __builtin_amdgcn_mfma_f32_16x16x32_bf16(a0, bf3, acc[0][3], 0, 0, 0);
            acc[1][3] = __builtin_amdgcn_mfma_f32_16x16x32_bf16(a1, bf3, acc[1][3], 0, 0, 0);
        }
    }

    // epilogue: hidden = relu(acc + b1[h]); per-edge sum of hidden*w2[h]
    float b1v[4], w2v[4];
    #pragma unroll
    for (int j = 0; j < 4; ++j) {
        int h = wave * 64 + j * 16 + colA;
        b1v[j] = b1[h];
        w2v[j] = w2[h];
    }

    #pragma unroll
    for (int t = 0; t < 2; ++t) {
        #pragma unroll
        for (int r = 0; r < 4; ++r) {
            float s = 0.0f;
            #pragma unroll
            for (int j = 0; j < 4; ++j) {
                float h = acc[t][j][r] + b1v[j];
                s += fmaxf(h, 0.0f) * w2v[j];
            }
            s += __shfl_xor(s, 1);
            s += __shfl_xor(s, 2);
            s += __shfl_xor(s, 4);
            s += __shfl_xor(s, 8);
            if (colA == 0) {
                int m = 16 * t + quad * 4 + r;
                red[wave][m] = s;
            }
        }
    }
    __syncthreads();

    if (tid < 32) {
        int m = tid;
        if (m < nm) {
            float sc = red[0][m] + red[1][m] + red[2][m] + red[3][m] + b2[0];
            out[s_e[m]] = s_pv[m] * sc;
        }
    }
}

extern "C" void kernel_launch(void* const* d_in, const int* in_sizes, int n_in,
                              void* d_out, int out_size, void* d_ws, size_t ws_size,
                              hipStream_t stream)
{
    const float* z   = (const float*)d_in[0];
    const int*   u   = (const int*)d_in[1];
    const int*   v   = (const int*)d_in[2];
    const float* gw  = (const float*)d_in[3];
    const float* gb  = (const float*)d_in[4];
    const float* cw1 = (const float*)d_in[5];
    const float* cb1 = (const float*)d_in[6];
    const float* cw2 = (const float*)d_in[7];
    const float* cb2 = (const float*)d_in[8];
    const float* dw1 = (const float*)d_in[9];
    const float* db1 = (const float*)d_in[10];
    const float* dw2 = (const float*)d_in[11];
    const float* db2 = (const float*)d_in[12];
    const float* mw1 = (const float*)d_in[13];
    const float* mb1 = (const float*)d_in[14];
    const float* mw2 = (const float*)d_in[15];
    const float* mb2 = (const float*)d_in[16];
    const float* aw1 = (const float*)d_in[17];
    const float* ab1 = (const float*)d_in[18];
    const float* aw2 = (const float*)d_in[19];
    const float* ab2 = (const float*)d_in[20];

    float* out = (float*)d_out;
    char*  ws  = (char*)d_ws;

    float*          probsum = (float*)ws;
    unsigned*       gcount  = (unsigned*)(ws + 16);
    int*            lists   = (int*)(ws + 32);
    float*          pval    = (float*)(ws + 32 + 16ll * E_EDGES);
    unsigned short* w1b     = (unsigned short*)(ws + 32 + 20ll * E_EDGES);
    double*         gwd     = (double*)(ws + 32 + 20ll * E_EDGES + 524288);
    double*         nodeTab = (double*)(ws + 32 + 20ll * E_EDGES + 524288 + 8192);

    hipMemsetAsync(d_ws, 0, 32, stream);

    prep_kernel<<<1024 + (N_NODES + 255) / 256, 256, 0, stream>>>(
        cw1, dw1, mw1, aw1, w1b, z, gw, nodeTab, gwd);

    gate_kernel<<<E_EDGES / 128, 256, 0, stream>>>(z, u, v, nodeTab, gwd, gb,
                                                   probsum, gcount, lists, pval);

    dim3 g2(E_EDGES / 32, 4);
    expert_kernel<<<g2, 256, 0, stream>>>(z, u, v, w1b,
                                          cb1, cw2, cb2,
                                          db1, dw2, db2,
                                          mb1, mw2, mb2,
                                          ab1, aw2, ab2,
                                          gcount, lists, pval, probsum, out);
}